// Round 1
// baseline (17637.065 us; speedup 1.0000x reference)
//
#include <hip/hip_runtime.h>
#include <math.h>

// Problem constants (from reference setup_inputs)
static constexpr int B_ = 32;
static constexpr int S_ = 2048;
static constexpr int E_ = 512;
static constexpr int V_ = 32000;
static constexpr float EPS_ = 1e-6f;

// ---------------------------------------------------------------------------
// K1: sequential scan. One block per batch element, 1024 threads (16 waves).
// z kept in LDS. W_dec streamed from global (L2-resident, 1 MB/step/CU).
// Matvec split: slice s = tid/128 covers rows i in [s*64, s*64+64);
// colgroup cg = tid%128 covers columns 4cg..4cg+3 (float4 coalesced loads).
// ---------------------------------------------------------------------------
__global__ __launch_bounds__(1024) void scan_kernel(
    const int* __restrict__ seq,     // (B,S)
    const float* __restrict__ emb,   // (V,E)
    const float* __restrict__ Wdec,  // (E,E) row-major
    const float* __restrict__ bdec,  // (E)
    const float* __restrict__ gamma, // (E)
    const float* __restrict__ beta,  // (E)
    float* __restrict__ zout)        // (B,E)
{
    __shared__ float z[E_];
    __shared__ float part[8][E_];
    __shared__ float red[8];

    const int b    = blockIdx.x;
    const int tid  = threadIdx.x;
    const int s    = tid >> 7;    // 0..7
    const int cg   = tid & 127;   // 0..127
    const int lane = tid & 63;
    const int wv   = tid >> 6;
    const bool act = tid < E_;

    float gj = 0.f, bj = 0.f, bdj = 0.f;
    if (act) {
        gj  = gamma[tid];
        bj  = beta[tid];
        bdj = bdec[tid];
        z[tid] = 0.0f;
    }
    __syncthreads();

    const float sqrtE = sqrtf((float)E_);
    const int* seqb = seq + (size_t)b * S_;
    const float* wbase = Wdec + (size_t)(s * 64) * E_ + 4 * cg;
    const int ibase = s * 64;

    for (int t = 0; t < S_; ++t) {
        const int tok = seqb[t];
        float zin = 0.f;
        if (act) {
            zin = z[tid] + emb[(size_t)tok * E_ + tid] * sqrtE;
            z[tid] = zin;   // only thread tid reads old z[tid] (above)
        }
        __syncthreads();    // z now holds z_in for everyone

        // partial matvec: acc[k] = sum_{ii} z_in[ibase+ii] * W[ibase+ii][4cg+k]
        float4 acc = make_float4(0.f, 0.f, 0.f, 0.f);
        #pragma unroll 8
        for (int ii = 0; ii < 64; ++ii) {
            const float zi = z[ibase + ii];                      // LDS broadcast
            const float4 w = *(const float4*)(wbase + (size_t)ii * E_);
            acc.x = fmaf(zi, w.x, acc.x);
            acc.y = fmaf(zi, w.y, acc.y);
            acc.z = fmaf(zi, w.z, acc.z);
            acc.w = fmaf(zi, w.w, acc.w);
        }
        *(float4*)&part[s][4 * cg] = acc;
        __syncthreads();

        // z_mid[j] = z_in[j] + (dot + b_dec[j])
        float zmid = 0.f;
        if (act) {
            float h = bdj;
            #pragma unroll
            for (int k = 0; k < 8; ++k) h += part[k][tid];
            zmid = zin + h;
        }

        // mean
        float sv = zmid;
        #pragma unroll
        for (int off = 32; off > 0; off >>= 1) sv += __shfl_down(sv, off);
        if (act && lane == 0) red[wv] = sv;
        __syncthreads();
        float tot = 0.f;
        #pragma unroll
        for (int k = 0; k < 8; ++k) tot += red[k];
        const float mu = tot * (1.0f / E_);

        // variance (two-pass for accuracy, ddof=1)
        const float d = act ? (zmid - mu) : 0.f;
        float sq = d * d;
        #pragma unroll
        for (int off = 32; off > 0; off >>= 1) sq += __shfl_down(sq, off);
        __syncthreads();             // protect red reuse
        if (act && lane == 0) red[wv] = sq;
        __syncthreads();
        float tq = 0.f;
        #pragma unroll
        for (int k = 0; k < 8; ++k) tq += red[k];
        const float var = tq * (1.0f / (E_ - 1));
        const float denom = sqrtf(var) + EPS_;

        if (act) z[tid] = gj * d / denom + bj;
        __syncthreads();
    }

    if (act) zout[(size_t)b * E_ + tid] = z[tid];
}

// ---------------------------------------------------------------------------
// K2: logits = z @ W_voc + b_voc, written raw into y region of d_out.
// Grid (32 vocab tiles of 1024 cols, 4 batch-groups of 8). Each block loads
// 8 z-rows into LDS and reuses each W_voc float4 across 8 batches.
// ---------------------------------------------------------------------------
__global__ __launch_bounds__(256) void logits_kernel(
    const float* __restrict__ zfin,  // (B,E)
    const float* __restrict__ Wvoc,  // (E,V)
    const float* __restrict__ bvoc,  // (V)
    float* __restrict__ y)           // (B,V)
{
    __shared__ float zl[8 * E_];
    const int tile = blockIdx.x;
    const int bg   = blockIdx.y;
    const int tid  = threadIdx.x;

    for (int k = tid; k < 8 * E_; k += 256)
        zl[k] = zfin[(size_t)bg * 8 * E_ + k];
    __syncthreads();

    const int v0 = tile * 1024 + tid * 4;
    if (v0 >= V_) return;

    float4 acc[8];
    #pragma unroll
    for (int g = 0; g < 8; ++g) acc[g] = make_float4(0.f, 0.f, 0.f, 0.f);

    const float* wp = Wvoc + v0;
    #pragma unroll 4
    for (int i = 0; i < E_; ++i) {
        const float4 w = *(const float4*)(wp + (size_t)i * V_);
        #pragma unroll
        for (int g = 0; g < 8; ++g) {
            const float zi = zl[g * E_ + i];
            acc[g].x = fmaf(zi, w.x, acc[g].x);
            acc[g].y = fmaf(zi, w.y, acc[g].y);
            acc[g].z = fmaf(zi, w.z, acc[g].z);
            acc[g].w = fmaf(zi, w.w, acc[g].w);
        }
    }

    const float4 bv = *(const float4*)(bvoc + v0);
    #pragma unroll
    for (int g = 0; g < 8; ++g) {
        acc[g].x += bv.x; acc[g].y += bv.y; acc[g].z += bv.z; acc[g].w += bv.w;
        *(float4*)(y + (size_t)(bg * 8 + g) * V_ + v0) = acc[g];
    }
}

// ---------------------------------------------------------------------------
// K3: per-row (batch) log-sum-exp correction: corr[b] = max + log(sum exp(x-max))
// ---------------------------------------------------------------------------
__global__ __launch_bounds__(256) void lse_kernel(
    const float* __restrict__ y, float* __restrict__ corr)
{
    __shared__ float redm[4], redl[4];
    const int b = blockIdx.x;
    const int tid = threadIdx.x;
    const float* row = y + (size_t)b * V_;

    float m = -3.0e38f, l = 0.f;
    for (int v = tid; v < V_; v += 256) {
        const float x = row[v];
        const float nm = fmaxf(m, x);
        l = l * expf(m - nm) + expf(x - nm);
        m = nm;
    }
    #pragma unroll
    for (int off = 32; off > 0; off >>= 1) {
        const float om = __shfl_down(m, off);
        const float ol = __shfl_down(l, off);
        const float nm = fmaxf(m, om);
        l = l * expf(m - nm) + ol * expf(om - nm);
        m = nm;
    }
    const int lane = tid & 63, wv = tid >> 6;
    if (lane == 0) { redm[wv] = m; redl[wv] = l; }
    __syncthreads();
    if (tid == 0) {
        float M = redm[0], L = redl[0];
        for (int k = 1; k < 4; ++k) {
            const float nm = fmaxf(M, redm[k]);
            L = L * expf(M - nm) + redl[k] * expf(redm[k] - nm);
            M = nm;
        }
        corr[b] = M + logf(L);
    }
}

// ---------------------------------------------------------------------------
// K4: y -= corr[b] (in place), float4-vectorized. 32000 % 4 == 0 so a float4
// never crosses a row boundary.
// ---------------------------------------------------------------------------
__global__ __launch_bounds__(256) void fix_kernel(
    float* __restrict__ y, const float* __restrict__ corr)
{
    const int idx = blockIdx.x * 256 + threadIdx.x;   // float4 index
    const int o = idx * 4;
    const int b = o / V_;
    const float c = corr[b];
    float4 v = *(float4*)(y + o);
    v.x -= c; v.y -= c; v.z -= c; v.w -= c;
    *(float4*)(y + o) = v;
}

// ---------------------------------------------------------------------------
extern "C" void kernel_launch(void* const* d_in, const int* in_sizes, int n_in,
                              void* d_out, int out_size, void* d_ws, size_t ws_size,
                              hipStream_t stream)
{
    (void)in_sizes; (void)n_in; (void)out_size; (void)ws_size;
    // inputs: 0=hidden_state (unused), 1=output_sequence, 2=emb_out, 3=W_dec,
    //         4=b_dec, 5=gamma, 6=beta, 7=W_voc, 8=b_voc
    const int*   seq  = (const int*)  d_in[1];
    const float* emb  = (const float*)d_in[2];
    const float* Wdec = (const float*)d_in[3];
    const float* bdec = (const float*)d_in[4];
    const float* gam  = (const float*)d_in[5];
    const float* bet  = (const float*)d_in[6];
    const float* Wvoc = (const float*)d_in[7];
    const float* bvoc = (const float*)d_in[8];

    float* out  = (float*)d_out;
    float* zout = out;            // B*E floats
    float* y    = out + B_ * E_;  // B*V floats
    float* corr = (float*)d_ws;   // 32 floats of scratch

    hipLaunchKernelGGL(scan_kernel, dim3(B_), dim3(1024), 0, stream,
                       seq, emb, Wdec, bdec, gam, bet, zout);
    hipLaunchKernelGGL(logits_kernel, dim3(32, 4), dim3(256), 0, stream,
                       zout, Wvoc, bvoc, y);
    hipLaunchKernelGGL(lse_kernel, dim3(B_), dim3(256), 0, stream, y, corr);
    hipLaunchKernelGGL(fix_kernel, dim3(1000), dim3(256), 0, stream, y, corr);
}